// Round 1
// baseline (2103.936 us; speedup 1.0000x reference)
//
#include <hip/hip_runtime.h>
#include <hip/hip_bf16.h>
#include <cstdint>
#include <cstddef>

// Problem constants (match reference)
#define BB   8
#define NN   4096
#define CC   64
#define KK   16
#define INCH 131
#define H2   128
#define NPOSF 524288.0f   // B*N*K
#define BNEPS 1e-5f

// ---------- helpers ----------
__device__ __forceinline__ unsigned short f2bf(float x) {
  union { float f; unsigned u; } v; v.f = x;
  unsigned u = v.u;
  return (unsigned short)((u + 0x7fffu + ((u >> 16) & 1u)) >> 16);
}
__device__ __forceinline__ float bf2f(unsigned short h) {
  union { unsigned u; float f; } v; v.u = ((unsigned)h) << 16; return v.f;
}
__device__ __forceinline__ void store4bf(unsigned short* p, float4 v) {
  ushort4 u; u.x = f2bf(v.x); u.y = f2bf(v.y); u.z = f2bf(v.z); u.w = f2bf(v.w);
  *(ushort4*)p = u;
}

#define FMA4(acc, w4, s) { acc.x += w4.x*(s); acc.y += w4.y*(s); acc.z += w4.z*(s); acc.w += w4.w*(s); }

// ---------- tiny utility kernels ----------
__global__ __launch_bounds__(512) void k_zero(float* p) {
  p[threadIdx.x] = 0.f;   // 512 floats of stats
}

// pos2t[b][n] = (x,y,z, x^2+y^2+z^2)  from pos2 [B,3,N]
__global__ __launch_bounds__(256) void k_pos2t(const float* __restrict__ pos2, float4* __restrict__ out) {
  int i = blockIdx.x * 256 + threadIdx.x;       // 0..32767
  int b = i >> 12, n = i & 4095;
  float x = pos2[(b*3 + 0)*NN + n];
  float y = pos2[(b*3 + 1)*NN + n];
  float z = pos2[(b*3 + 2)*NN + n];
  float w = (x*x + y*y) + z*z;                  // same assoc as reference r2
  out[i] = make_float4(x, y, z, w);
}

// [B,64,N] -> [B,N,64]
__global__ __launch_bounds__(256) void k_transpose(const float* __restrict__ in, float* __restrict__ out) {
  __shared__ float tile[32][33];
  int b = blockIdx.z;
  int n0 = blockIdx.x * 32, c0 = blockIdx.y * 32;
  int tx = threadIdx.x, ty = threadIdx.y;
  #pragma unroll
  for (int i = 0; i < 32; i += 8)
    tile[ty + i][tx] = in[((size_t)(b*CC + c0 + ty + i))*NN + n0 + tx];
  __syncthreads();
  #pragma unroll
  for (int i = 0; i < 32; i += 8)
    out[((size_t)(b*NN + n0 + ty + i))*CC + c0 + tx] = tile[tx][ty + i];
}

// ---------- KNN: thread-per-query, refs staged in LDS chunks ----------
__global__ __launch_bounds__(128) void k_knn(const float* __restrict__ pos1_re,
                                             const float4* __restrict__ pos2t,
                                             int* __restrict__ idxOut) {
  extern __shared__ float4 ref[];               // 2048 float4 = 32 KB
  const int b = blockIdx.y;
  const int n = blockIdx.x * 128 + threadIdx.x;

  const float qx = pos1_re[(b*3 + 0)*NN + n];
  const float qy = pos1_re[(b*3 + 1)*NN + n];
  const float qz = pos1_re[(b*3 + 2)*NN + n];
  const float q2 = (qx*qx + qy*qy) + qz*qz;

  float bd[KK]; int bi[KK];
  #pragma unroll
  for (int j = 0; j < KK; ++j) { bd[j] = 3.4e38f; bi[j] = 0; }
  float wv = 3.4e38f;

  for (int ch0 = 0; ch0 < NN; ch0 += 2048) {
    __syncthreads();
    for (int i = threadIdx.x; i < 2048; i += 128) ref[i] = pos2t[b*NN + ch0 + i];
    __syncthreads();
    for (int mm = 0; mm < 2048; ++mm) {
      float4 r = ref[mm];
      float dot = qx*r.x + qy*r.y + qz*r.z;
      float d = (q2 + r.w) - 2.0f*dot;          // reference formula/assoc
      if (d < wv) {
        int m = ch0 + mm;
        bool done = false;
        #pragma unroll
        for (int j = 0; j < KK; ++j) {
          bool hit = (!done) && (bd[j] == wv);
          if (hit) { bd[j] = d; bi[j] = m; }
          done = done || hit;
        }
        wv = bd[0];
        #pragma unroll
        for (int j = 1; j < KK; ++j) wv = fmaxf(wv, bd[j]);
      }
    }
  }
  #pragma unroll
  for (int j = 0; j < KK; ++j) idxOut[((size_t)(b*NN + n))*KK + j] = bi[j];
}

// ---------- layer 0: gather -> x[131] -> y0 = W0 x ; stats ----------
// block = 128 threads (2 waves), each wave = one n (16 k-positions x 64 ch)
#define RED4(A0_,A1_,A2_,A3_, comp, chidx) { \
  float s_ = A0_.comp + A1_.comp + A2_.comp + A3_.comp; \
  float q_ = A0_.comp*A0_.comp + A1_.comp*A1_.comp + A2_.comp*A2_.comp + A3_.comp*A3_.comp; \
  s_ += __shfl_xor(s_, 16); s_ += __shfl_xor(s_, 32); \
  q_ += __shfl_xor(q_, 16); q_ += __shfl_xor(q_, 32); \
  if (pg == 0) { atomicAdd(&sS[chidx], s_); atomicAdd(&sQ[chidx], q_); } \
}

__global__ __launch_bounds__(128) void k_layer0(
    const int* __restrict__ nidx, const float4* __restrict__ pos2t,
    const float* __restrict__ pos1, const float* __restrict__ f2t,
    const float* __restrict__ f1t, const float* __restrict__ W0,
    unsigned short* __restrict__ Y0, float* __restrict__ gS, float* __restrict__ gQ) {
  extern __shared__ float sm[];
  float* wsL = sm;                         // 131*64 = 8384
  float* xs  = sm + 8384;                  // 2*131*16 = 4192
  float* sS  = sm + 8384 + 4192;           // 64
  float* sQ  = sS + 64;                    // 64
  int*   mI  = (int*)(sQ + 64);            // 32

  const int t = threadIdx.x;
  const int b = blockIdx.y;
  const int n0 = blockIdx.x * 2;

  for (int i = t; i < INCH*64; i += 128) { int c = i >> 6, o = i & 63; wsL[i] = W0[o*INCH + c]; }
  sS[t] = 0.f;                             // t<128 covers sS[64]+sQ[64]
  if (t < 32) mI[t] = nidx[((size_t)(b*NN + n0 + (t >> 4)))*KK + (t & 15)];
  __syncthreads();

  const int w = t >> 6, lane = t & 63;
  const int kq = lane >> 2, cg = lane & 3;
  const int n = n0 + w;
  float* xw = xs + w*(INCH*16);
  {
    const int m = mI[w*16 + kq];
    const float* f2row = f2t + ((size_t)(b*NN + m))*64;
    const float* f1row = f1t + ((size_t)(b*NN + n))*64;
    #pragma unroll
    for (int it = 0; it < 4; ++it) {
      int c = it*16 + cg*4;
      float4 v2 = *(const float4*)(f2row + c);
      float4 v1 = *(const float4*)(f1row + c);
      xw[(3 + c + 0)*16 + kq] = v2.x;
      xw[(3 + c + 1)*16 + kq] = v2.y;
      xw[(3 + c + 2)*16 + kq] = v2.z;
      xw[(3 + c + 3)*16 + kq] = v2.w;
      xw[(67 + c + 0)*16 + kq] = v1.x;
      xw[(67 + c + 1)*16 + kq] = v1.y;
      xw[(67 + c + 2)*16 + kq] = v1.z;
      xw[(67 + c + 3)*16 + kq] = v1.w;
    }
    if (lane < 16) {
      float4 p = pos2t[b*NN + mI[w*16 + lane]];
      float px = pos1[(b*3 + 0)*NN + n];
      float py = pos1[(b*3 + 1)*NN + n];
      float pz = pos1[(b*3 + 2)*NN + n];
      xw[0*16 + lane] = p.x - px;
      xw[1*16 + lane] = p.y - py;
      xw[2*16 + lane] = p.z - pz;
    }
  }
  __syncthreads();

  const int o4 = lane & 15, pg = lane >> 4;
  float4 a0 = {0,0,0,0}, a1 = {0,0,0,0}, a2 = {0,0,0,0}, a3 = {0,0,0,0};
  const float* wb = wsL + 4*o4;
  const float* xb = xw + 4*pg;
  #pragma unroll 4
  for (int c = 0; c < INCH; ++c) {
    float4 w4 = *(const float4*)(wb + c*64);
    float4 xv = *(const float4*)(xb + c*16);
    FMA4(a0, w4, xv.x); FMA4(a1, w4, xv.y); FMA4(a2, w4, xv.z); FMA4(a3, w4, xv.w);
  }
  {
    size_t base = ((size_t)(b*NN + n))*KK;
    store4bf(Y0 + (base + pg*4 + 0)*64 + 4*o4, a0);
    store4bf(Y0 + (base + pg*4 + 1)*64 + 4*o4, a1);
    store4bf(Y0 + (base + pg*4 + 2)*64 + 4*o4, a2);
    store4bf(Y0 + (base + pg*4 + 3)*64 + 4*o4, a3);
  }
  RED4(a0,a1,a2,a3, x, 4*o4 + 0)
  RED4(a0,a1,a2,a3, y, 4*o4 + 1)
  RED4(a0,a1,a2,a3, z, 4*o4 + 2)
  RED4(a0,a1,a2,a3, w, 4*o4 + 3)
  __syncthreads();
  if (t < 64) { atomicAdd(&gS[t], sS[t]); atomicAdd(&gQ[t], sQ[t]); }
}

// ---------- finalize BN stats -> per-channel alpha/beta ----------
__global__ __launch_bounds__(128) void k_finalize(const float* __restrict__ S, const float* __restrict__ Q,
                                                  const float* __restrict__ g, const float* __restrict__ bb_,
                                                  float* __restrict__ A, float* __restrict__ Bt, int ch) {
  int t = threadIdx.x;
  if (t < ch) {
    float mean = S[t] * (1.0f / NPOSF);
    float var  = Q[t] * (1.0f / NPOSF) - mean*mean;
    float rs   = 1.0f / sqrtf(var + BNEPS);
    float a    = g[t] * rs;
    A[t] = a; Bt[t] = bb_[t] - mean*a;
  }
}

// ---------- layer 1: a1 = relu(alpha0*y0+beta0); y1 = W1 a1 ; stats ----------
__global__ __launch_bounds__(256) void k_layer1(
    const unsigned short* __restrict__ Y0, const float* __restrict__ A0, const float* __restrict__ B0,
    const float* __restrict__ W1, unsigned short* __restrict__ Y1,
    float* __restrict__ gS, float* __restrict__ gQ) {
  extern __shared__ float sm[];
  float* wsL = sm;            // 4096
  float* xs  = sm + 4096;     // 4096
  float* aL  = sm + 8192;     // 64
  float* bL  = aL + 64;       // 64
  float* sS  = bL + 64;       // 64
  float* sQ  = sS + 64;       // 64

  const int t = threadIdx.x;
  const int b = blockIdx.y, n0 = blockIdx.x * 4;
  for (int i = t; i < 64*64; i += 256) { int c = i >> 6, o = i & 63; wsL[i] = W1[o*64 + c]; }
  if (t < 64)  { aL[t] = A0[t]; bL[t] = B0[t]; }
  if (t < 128) { sS[t] = 0.f; }
  __syncthreads();

  const int w = t >> 6, lane = t & 63, kq = lane >> 2, cg = lane & 3;
  const int n = n0 + w;
  float* xw = xs + w*1024;
  const unsigned short* yrow = Y0 + (((size_t)(b*NN + n))*KK + kq)*64;
  #pragma unroll
  for (int it = 0; it < 4; ++it) {
    int c = it*16 + cg*4;
    ushort4 u = *(const ushort4*)(yrow + c);
    xw[(c + 0)*16 + kq] = fmaxf(bf2f(u.x)*aL[c + 0] + bL[c + 0], 0.f);
    xw[(c + 1)*16 + kq] = fmaxf(bf2f(u.y)*aL[c + 1] + bL[c + 1], 0.f);
    xw[(c + 2)*16 + kq] = fmaxf(bf2f(u.z)*aL[c + 2] + bL[c + 2], 0.f);
    xw[(c + 3)*16 + kq] = fmaxf(bf2f(u.w)*aL[c + 3] + bL[c + 3], 0.f);
  }
  __syncthreads();

  const int o4 = lane & 15, pg = lane >> 4;
  float4 a0 = {0,0,0,0}, a1 = {0,0,0,0}, a2 = {0,0,0,0}, a3 = {0,0,0,0};
  const float* wb = wsL + 4*o4;
  const float* xb = xw + 4*pg;
  #pragma unroll 4
  for (int c = 0; c < 64; ++c) {
    float4 w4 = *(const float4*)(wb + c*64);
    float4 xv = *(const float4*)(xb + c*16);
    FMA4(a0, w4, xv.x); FMA4(a1, w4, xv.y); FMA4(a2, w4, xv.z); FMA4(a3, w4, xv.w);
  }
  {
    size_t base = ((size_t)(b*NN + n))*KK;
    store4bf(Y1 + (base + pg*4 + 0)*64 + 4*o4, a0);
    store4bf(Y1 + (base + pg*4 + 1)*64 + 4*o4, a1);
    store4bf(Y1 + (base + pg*4 + 2)*64 + 4*o4, a2);
    store4bf(Y1 + (base + pg*4 + 3)*64 + 4*o4, a3);
  }
  RED4(a0,a1,a2,a3, x, 4*o4 + 0)
  RED4(a0,a1,a2,a3, y, 4*o4 + 1)
  RED4(a0,a1,a2,a3, z, 4*o4 + 2)
  RED4(a0,a1,a2,a3, w, 4*o4 + 3)
  __syncthreads();
  if (t < 64) { atomicAdd(&gS[t], sS[t]); atomicAdd(&gQ[t], sQ[t]); }
}

// ---------- layer 2 shared staging+compute (128 out channels) ----------
// stats pass: accumulate sum/sumsq of y2; final pass: bn2+relu+max over k -> out
__global__ __launch_bounds__(256) void k_l2stats(
    const unsigned short* __restrict__ Y1, const float* __restrict__ A1, const float* __restrict__ B1,
    const float* __restrict__ W2, float* __restrict__ gS, float* __restrict__ gQ) {
  extern __shared__ float sm[];
  float* wsL = sm;            // 64*128 = 8192
  float* xs  = sm + 8192;     // 4096
  float* aL  = sm + 12288;    // 64
  float* bL  = aL + 64;       // 64
  float* sS  = bL + 64;       // 128
  float* sQ  = sS + 128;      // 128

  const int t = threadIdx.x;
  const int b = blockIdx.y, n0 = blockIdx.x * 4;
  for (int i = t; i < 64*128; i += 256) { int c = i >> 7, o = i & 127; wsL[i] = W2[o*64 + c]; }
  if (t < 64) { aL[t] = A1[t]; bL[t] = B1[t]; }
  sS[t] = 0.f;                // t<256 covers sS[128]+sQ[128]
  __syncthreads();

  const int w = t >> 6, lane = t & 63, kq = lane >> 2, cg = lane & 3;
  const int n = n0 + w;
  float* xw = xs + w*1024;
  const unsigned short* yrow = Y1 + (((size_t)(b*NN + n))*KK + kq)*64;
  #pragma unroll
  for (int it = 0; it < 4; ++it) {
    int c = it*16 + cg*4;
    ushort4 u = *(const ushort4*)(yrow + c);
    xw[(c + 0)*16 + kq] = fmaxf(bf2f(u.x)*aL[c + 0] + bL[c + 0], 0.f);
    xw[(c + 1)*16 + kq] = fmaxf(bf2f(u.y)*aL[c + 1] + bL[c + 1], 0.f);
    xw[(c + 2)*16 + kq] = fmaxf(bf2f(u.z)*aL[c + 2] + bL[c + 2], 0.f);
    xw[(c + 3)*16 + kq] = fmaxf(bf2f(u.w)*aL[c + 3] + bL[c + 3], 0.f);
  }
  __syncthreads();

  const int o4 = lane & 15, pg = lane >> 4;
  float4 c00={0,0,0,0},c01={0,0,0,0},c02={0,0,0,0},c03={0,0,0,0};
  float4 c10={0,0,0,0},c11={0,0,0,0},c12={0,0,0,0},c13={0,0,0,0};
  const float* wbA = wsL + 4*o4;
  const float* wbB = wsL + 64 + 4*o4;
  const float* xb  = xw + 4*pg;
  #pragma unroll 4
  for (int c = 0; c < 64; ++c) {
    float4 xv = *(const float4*)(xb + c*16);
    float4 wA = *(const float4*)(wbA + c*128);
    float4 wB = *(const float4*)(wbB + c*128);
    FMA4(c00, wA, xv.x); FMA4(c01, wA, xv.y); FMA4(c02, wA, xv.z); FMA4(c03, wA, xv.w);
    FMA4(c10, wB, xv.x); FMA4(c11, wB, xv.y); FMA4(c12, wB, xv.z); FMA4(c13, wB, xv.w);
  }
  RED4(c00,c01,c02,c03, x, 4*o4 + 0)
  RED4(c00,c01,c02,c03, y, 4*o4 + 1)
  RED4(c00,c01,c02,c03, z, 4*o4 + 2)
  RED4(c00,c01,c02,c03, w, 4*o4 + 3)
  RED4(c10,c11,c12,c13, x, 64 + 4*o4 + 0)
  RED4(c10,c11,c12,c13, y, 64 + 4*o4 + 1)
  RED4(c10,c11,c12,c13, z, 64 + 4*o4 + 2)
  RED4(c10,c11,c12,c13, w, 64 + 4*o4 + 3)
  __syncthreads();
  if (t < 128) { atomicAdd(&gS[t], sS[t]); atomicAdd(&gQ[t], sQ[t]); }
}

#define MAXC(A0_,A1_,A2_,A3_, comp, chidx) { \
  int ch_ = (chidx); float al_ = aL2[ch_], be_ = bL2[ch_]; \
  float m_ = fmaxf(al_*A0_.comp + be_, 0.f); \
  m_ = fmaxf(m_, fmaxf(al_*A1_.comp + be_, 0.f)); \
  m_ = fmaxf(m_, fmaxf(al_*A2_.comp + be_, 0.f)); \
  m_ = fmaxf(m_, fmaxf(al_*A3_.comp + be_, 0.f)); \
  m_ = fmaxf(m_, __shfl_xor(m_, 16)); m_ = fmaxf(m_, __shfl_xor(m_, 32)); \
  if (pg == 0) oBuf[w*128 + ch_] = m_; \
}

__global__ __launch_bounds__(256) void k_l2final(
    const unsigned short* __restrict__ Y1, const float* __restrict__ A1, const float* __restrict__ B1,
    const float* __restrict__ W2, const float* __restrict__ A2, const float* __restrict__ B2,
    float* __restrict__ outF) {
  extern __shared__ float sm[];
  float* wsL  = sm;            // 8192
  float* xs   = sm + 8192;     // 4096
  float* aL   = sm + 12288;    // 64
  float* bL   = aL + 64;       // 64
  float* aL2  = bL + 64;       // 128
  float* bL2  = aL2 + 128;     // 128
  float* oBuf = bL2 + 128;     // 512

  const int t = threadIdx.x;
  const int b = blockIdx.y, n0 = blockIdx.x * 4;
  for (int i = t; i < 64*128; i += 256) { int c = i >> 7, o = i & 127; wsL[i] = W2[o*64 + c]; }
  if (t < 64)  { aL[t] = A1[t]; bL[t] = B1[t]; }
  if (t < 128) { aL2[t] = A2[t]; bL2[t] = B2[t]; }
  __syncthreads();

  const int w = t >> 6, lane = t & 63, kq = lane >> 2, cg = lane & 3;
  const int n = n0 + w;
  float* xw = xs + w*1024;
  const unsigned short* yrow = Y1 + (((size_t)(b*NN + n))*KK + kq)*64;
  #pragma unroll
  for (int it = 0; it < 4; ++it) {
    int c = it*16 + cg*4;
    ushort4 u = *(const ushort4*)(yrow + c);
    xw[(c + 0)*16 + kq] = fmaxf(bf2f(u.x)*aL[c + 0] + bL[c + 0], 0.f);
    xw[(c + 1)*16 + kq] = fmaxf(bf2f(u.y)*aL[c + 1] + bL[c + 1], 0.f);
    xw[(c + 2)*16 + kq] = fmaxf(bf2f(u.z)*aL[c + 2] + bL[c + 2], 0.f);
    xw[(c + 3)*16 + kq] = fmaxf(bf2f(u.w)*aL[c + 3] + bL[c + 3], 0.f);
  }
  __syncthreads();

  const int o4 = lane & 15, pg = lane >> 4;
  float4 c00={0,0,0,0},c01={0,0,0,0},c02={0,0,0,0},c03={0,0,0,0};
  float4 c10={0,0,0,0},c11={0,0,0,0},c12={0,0,0,0},c13={0,0,0,0};
  const float* wbA = wsL + 4*o4;
  const float* wbB = wsL + 64 + 4*o4;
  const float* xb  = xw + 4*pg;
  #pragma unroll 4
  for (int c = 0; c < 64; ++c) {
    float4 xv = *(const float4*)(xb + c*16);
    float4 wA = *(const float4*)(wbA + c*128);
    float4 wB = *(const float4*)(wbB + c*128);
    FMA4(c00, wA, xv.x); FMA4(c01, wA, xv.y); FMA4(c02, wA, xv.z); FMA4(c03, wA, xv.w);
    FMA4(c10, wB, xv.x); FMA4(c11, wB, xv.y); FMA4(c12, wB, xv.z); FMA4(c13, wB, xv.w);
  }
  MAXC(c00,c01,c02,c03, x, 4*o4 + 0)
  MAXC(c00,c01,c02,c03, y, 4*o4 + 1)
  MAXC(c00,c01,c02,c03, z, 4*o4 + 2)
  MAXC(c00,c01,c02,c03, w, 4*o4 + 3)
  MAXC(c10,c11,c12,c13, x, 64 + 4*o4 + 0)
  MAXC(c10,c11,c12,c13, y, 64 + 4*o4 + 1)
  MAXC(c10,c11,c12,c13, z, 64 + 4*o4 + 2)
  MAXC(c10,c11,c12,c13, w, 64 + 4*o4 + 3)
  __syncthreads();
  #pragma unroll
  for (int e = t; e < 512; e += 256) {
    int ch = e >> 2, nl = e & 3;
    outF[((size_t)b*H2 + ch)*NN + n0 + nl] = oBuf[nl*128 + ch];
  }
}

// ---------- launch ----------
extern "C" void kernel_launch(void* const* d_in, const int* in_sizes, int n_in,
                              void* d_out, int out_size, void* d_ws, size_t ws_size,
                              hipStream_t stream) {
  const float* pos1    = (const float*)d_in[0];
  const float* pos1_re = (const float*)d_in[1];
  const float* pos2    = (const float*)d_in[2];
  const float* f1      = (const float*)d_in[3];
  const float* f2      = (const float*)d_in[4];
  const float* W0 = (const float*)d_in[6];
  const float* g0 = (const float*)d_in[7];
  const float* b0 = (const float*)d_in[8];
  const float* W1 = (const float*)d_in[9];
  const float* g1 = (const float*)d_in[10];
  const float* b1 = (const float*)d_in[11];
  const float* W2 = (const float*)d_in[12];
  const float* g2 = (const float*)d_in[13];
  const float* b2 = (const float*)d_in[14];
  float* out = (float*)d_out;

  // workspace layout (bytes)
  char* ws = (char*)d_ws;
  float* stats = (float*)ws;                 // 512 floats: S0 Q0 S1 Q1 S2 Q2
  float* S0 = stats;       float* Q0 = stats + 64;
  float* S1 = stats + 128; float* Q1 = stats + 192;
  float* S2 = stats + 256; float* Q2 = stats + 384;
  float* prm = stats + 512;                  // 512 floats: A0 B0 A1 B1 A2 B2
  float* A0 = prm;       float* B0a = prm + 64;
  float* A1 = prm + 128; float* B1a = prm + 192;
  float* A2 = prm + 256; float* B2a = prm + 384;
  int*    idxb  = (int*)(ws + 4096);
  float4* pos2t = (float4*)(ws + 4096 + 2097152);
  float*  f2t   = (float*)(ws + 2625536);
  float*  f1t   = f2t + (size_t)BB*NN*CC;
  unsigned short* Y0 = (unsigned short*)(ws + 19402752);
  unsigned short* Y1 = Y0 + (size_t)BB*NN*KK*64;
  // total = 153,620,480 bytes
  if (ws_size < 153620480u) return;   // fail loudly (validation will catch)

  k_zero<<<1, 512, 0, stream>>>(stats);
  hipMemcpyAsync(out, pos1, (size_t)BB*3*NN*sizeof(float), hipMemcpyDeviceToDevice, stream);

  k_pos2t<<<dim3(BB*NN/256), 256, 0, stream>>>(pos2, pos2t);
  k_transpose<<<dim3(NN/32, CC/32, BB), dim3(32, 8), 0, stream>>>(f2, f2t);
  k_transpose<<<dim3(NN/32, CC/32, BB), dim3(32, 8), 0, stream>>>(f1, f1t);
  k_knn<<<dim3(NN/128, BB), 128, 2048*sizeof(float4), stream>>>(pos1_re, pos2t, idxb);

  k_layer0<<<dim3(NN/2, BB), 128, 12736*4, stream>>>(idxb, pos2t, pos1, f2t, f1t, W0, Y0, S0, Q0);
  k_finalize<<<1, 128, 0, stream>>>(S0, Q0, g0, b0, A0, B0a, 64);

  k_layer1<<<dim3(NN/4, BB), 256, 8448*4, stream>>>(Y0, A0, B0a, W1, Y1, S1, Q1);
  k_finalize<<<1, 128, 0, stream>>>(S1, Q1, g1, b1, A1, B1a, 64);

  k_l2stats<<<dim3(NN/4, BB), 256, 12672*4, stream>>>(Y1, A1, B1a, W2, S2, Q2);
  k_finalize<<<1, 128, 0, stream>>>(S2, Q2, g2, b2, A2, B2a, 128);

  k_l2final<<<dim3(NN/4, BB), 256, 13184*4, stream>>>(Y1, A1, B1a, W2, A2, B2a, out + (size_t)BB*3*NN);
}

// Round 3
// 1439.170 us; speedup vs baseline: 1.4619x; 1.4619x over previous
//
#include <hip/hip_runtime.h>
#include <hip/hip_bf16.h>
#include <cstdint>
#include <cstddef>

#define BB   8
#define NN   4096
#define CC   64
#define KK   16
#define INCH 131
#define H2   128
#define NPOSF 524288.0f
#define BNEPS 1e-5f
#define FBIG 3.4e38f

// ---------- helpers ----------
__device__ __forceinline__ unsigned short f2bf(float x) {
  union { float f; unsigned u; } v; v.f = x;
  unsigned u = v.u;
  return (unsigned short)((u + 0x7fffu + ((u >> 16) & 1u)) >> 16);
}
__device__ __forceinline__ float bf2f(unsigned short h) {
  union { unsigned u; float f; } v; v.u = ((unsigned)h) << 16; return v.f;
}
__device__ __forceinline__ void store4bf(unsigned short* p, float4 v) {
  ushort4 u; u.x = f2bf(v.x); u.y = f2bf(v.y); u.z = f2bf(v.z); u.w = f2bf(v.w);
  *(ushort4*)p = u;
}

#define FMA4(acc, w4, s) { acc.x += w4.x*(s); acc.y += w4.y*(s); acc.z += w4.z*(s); acc.w += w4.w*(s); }

// ---------- utility kernels ----------
__global__ __launch_bounds__(256) void k_zero(float* p) {
  p[blockIdx.x * 256 + threadIdx.x] = 0.f;   // 16384 floats of stats
}

// pos2t[b][n] = (x,y,z, x^2+y^2+z^2)
__global__ __launch_bounds__(256) void k_pos2t(const float* __restrict__ pos2, float4* __restrict__ out) {
  int i = blockIdx.x * 256 + threadIdx.x;
  int b = i >> 12, n = i & 4095;
  float x = pos2[(b*3 + 0)*NN + n];
  float y = pos2[(b*3 + 1)*NN + n];
  float z = pos2[(b*3 + 2)*NN + n];
  float w = (x*x + y*y) + z*z;
  out[i] = make_float4(x, y, z, w);
}

// [B,64,N] -> [B,N,64]
__global__ __launch_bounds__(256) void k_transpose(const float* __restrict__ in, float* __restrict__ out) {
  __shared__ float tile[32][33];
  int b = blockIdx.z;
  int n0 = blockIdx.x * 32, c0 = blockIdx.y * 32;
  int tx = threadIdx.x, ty = threadIdx.y;
  #pragma unroll
  for (int i = 0; i < 32; i += 8)
    tile[ty + i][tx] = in[((size_t)(b*CC + c0 + ty + i))*NN + n0 + tx];
  __syncthreads();
  #pragma unroll
  for (int i = 0; i < 32; i += 8)
    out[((size_t)(b*NN + n0 + ty + i))*CC + c0 + tx] = tile[tx][ty + i];
}

// W -> Wt[c][o]
__global__ __launch_bounds__(256) void k_wt(const float* __restrict__ W0, const float* __restrict__ W1,
                                            const float* __restrict__ W2, float* __restrict__ Wt0,
                                            float* __restrict__ Wt1, float* __restrict__ Wt2) {
  int i = blockIdx.x * 256 + threadIdx.x;
  if (i < 8384) { int c = i >> 6, o = i & 63; Wt0[i] = W0[o*INCH + c]; }
  int j = i - 8384;
  if (j >= 0 && j < 4096) { int c = j >> 6, o = j & 63; Wt1[j] = W1[o*64 + c]; }
  int k2 = i - 12480;
  if (k2 >= 0 && k2 < 8192) { int c = k2 >> 7, o = k2 & 127; Wt2[k2] = W2[o*64 + c]; }
}

// ---------- KNN: R1 geometry/arithmetic verbatim; register-resident sorted insert ----------
// DO NOT restructure the mm loop or the d expression: selection is tie-fragile
// vs the np reference (R2 post-mortem) — this exact shape is validated.
__global__ __launch_bounds__(128) void k_knn(const float* __restrict__ pos1_re,
                                             const float4* __restrict__ pos2t,
                                             unsigned short* __restrict__ idxOut) {
  extern __shared__ float4 ref[];               // 2048 float4 = 32 KB
  const int b = blockIdx.y;
  const int n = blockIdx.x * 128 + threadIdx.x;

  const float qx = pos1_re[(b*3 + 0)*NN + n];
  const float qy = pos1_re[(b*3 + 1)*NN + n];
  const float qz = pos1_re[(b*3 + 2)*NN + n];
  const float q2 = (qx*qx + qy*qy) + qz*qz;

  float bd[KK]; int bi[KK];
  #pragma unroll
  for (int j = 0; j < KK; ++j) { bd[j] = FBIG; bi[j] = 0; }
  float wv = FBIG;

  for (int ch0 = 0; ch0 < NN; ch0 += 2048) {
    __syncthreads();
    for (int i = threadIdx.x; i < 2048; i += 128) ref[i] = pos2t[b*NN + ch0 + i];
    __syncthreads();
    for (int mm = 0; mm < 2048; ++mm) {
      float4 r = ref[mm];
      float dot = qx*r.x + qy*r.y + qz*r.z;
      float d = (q2 + r.w) - 2.0f*dot;          // reference formula/assoc
      if (d < wv) {
        float cd = d; int ci = ch0 + mm;
        #pragma unroll
        for (int j = 0; j < KK; ++j) {
          const bool lt = cd < bd[j];
          const float od = bd[j]; const int oi = bi[j];
          bd[j] = lt ? cd : od;
          bi[j] = lt ? ci : oi;
          cd = lt ? od : cd;
          ci = lt ? oi : ci;
        }
        wv = bd[KK-1];
      }
    }
  }
  unsigned short* outp = idxOut + ((size_t)(b*NN + n))*KK;
  #pragma unroll
  for (int j = 0; j < KK; ++j) outp[j] = (unsigned short)bi[j];
}

// ---------- stats reduction macro ----------
#define RED4(A0_,A1_,A2_,A3_, comp, chidx) { \
  float s_ = A0_.comp + A1_.comp + A2_.comp + A3_.comp; \
  float q_ = A0_.comp*A0_.comp + A1_.comp*A1_.comp + A2_.comp*A2_.comp + A3_.comp*A3_.comp; \
  s_ += __shfl_xor(s_, 16); s_ += __shfl_xor(s_, 32); \
  q_ += __shfl_xor(q_, 16); q_ += __shfl_xor(q_, 32); \
  if (pg == 0) { atomicAdd(&sS[chidx], s_); atomicAdd(&sQ[chidx], q_); } \
}

// ---------- layer 0 ----------
__global__ __launch_bounds__(128) void k_layer0(
    const unsigned short* __restrict__ nidx, const float4* __restrict__ pos2t,
    const float* __restrict__ pos1, const float* __restrict__ f2t,
    const float* __restrict__ f1t, const float* __restrict__ Wt0,
    unsigned short* __restrict__ Y0, float* __restrict__ gS, float* __restrict__ gQ) {
  extern __shared__ float sm[];
  float* wsL = sm;                         // 131*64 = 8384
  float* xs  = sm + 8384;                  // 2*131*16 = 4192
  float* sS  = sm + 8384 + 4192;           // 64
  float* sQ  = sS + 64;                    // 64
  int*   mI  = (int*)(sQ + 64);            // 32

  const int t = threadIdx.x;
  const int b = blockIdx.y;
  const int n0 = blockIdx.x * 2;

  for (int i = t; i < 2096; i += 128) ((float4*)wsL)[i] = ((const float4*)Wt0)[i];
  sS[t] = 0.f;
  if (t < 32) mI[t] = (int)nidx[((size_t)(b*NN + n0 + (t >> 4)))*KK + (t & 15)];
  __syncthreads();

  const int w = t >> 6, lane = t & 63;
  const int kq = lane >> 2, cg = lane & 3;
  const int n = n0 + w;
  float* xw = xs + w*(INCH*16);
  {
    const int m = mI[w*16 + kq];
    const float* f2row = f2t + ((size_t)(b*NN + m))*64;
    const float* f1row = f1t + ((size_t)(b*NN + n))*64;
    #pragma unroll
    for (int it = 0; it < 4; ++it) {
      int c = it*16 + cg*4;
      float4 v2 = *(const float4*)(f2row + c);
      float4 v1 = *(const float4*)(f1row + c);
      xw[(3 + c + 0)*16 + kq] = v2.x;
      xw[(3 + c + 1)*16 + kq] = v2.y;
      xw[(3 + c + 2)*16 + kq] = v2.z;
      xw[(3 + c + 3)*16 + kq] = v2.w;
      xw[(67 + c + 0)*16 + kq] = v1.x;
      xw[(67 + c + 1)*16 + kq] = v1.y;
      xw[(67 + c + 2)*16 + kq] = v1.z;
      xw[(67 + c + 3)*16 + kq] = v1.w;
    }
    if (lane < 16) {
      float4 p = pos2t[(size_t)b*NN + mI[w*16 + lane]];
      float px = pos1[(b*3 + 0)*NN + n];
      float py = pos1[(b*3 + 1)*NN + n];
      float pz = pos1[(b*3 + 2)*NN + n];
      xw[0*16 + lane] = p.x - px;
      xw[1*16 + lane] = p.y - py;
      xw[2*16 + lane] = p.z - pz;
    }
  }
  __syncthreads();

  const int o4 = lane & 15, pg = lane >> 4;
  float4 a0 = {0,0,0,0}, a1 = {0,0,0,0}, a2 = {0,0,0,0}, a3 = {0,0,0,0};
  const float* wb = wsL + 4*o4;
  const float* xb = xw + 4*pg;
  #pragma unroll 4
  for (int c = 0; c < INCH; ++c) {
    float4 w4 = *(const float4*)(wb + c*64);
    float4 xv = *(const float4*)(xb + c*16);
    FMA4(a0, w4, xv.x); FMA4(a1, w4, xv.y); FMA4(a2, w4, xv.z); FMA4(a3, w4, xv.w);
  }
  {
    size_t basep = ((size_t)(b*NN + n))*KK;
    store4bf(Y0 + (basep + pg*4 + 0)*64 + 4*o4, a0);
    store4bf(Y0 + (basep + pg*4 + 1)*64 + 4*o4, a1);
    store4bf(Y0 + (basep + pg*4 + 2)*64 + 4*o4, a2);
    store4bf(Y0 + (basep + pg*4 + 3)*64 + 4*o4, a3);
  }
  RED4(a0,a1,a2,a3, x, 4*o4 + 0)
  RED4(a0,a1,a2,a3, y, 4*o4 + 1)
  RED4(a0,a1,a2,a3, z, 4*o4 + 2)
  RED4(a0,a1,a2,a3, w, 4*o4 + 3)
  __syncthreads();
  const int slot = blockIdx.x & 31;
  if (t < 64) { atomicAdd(&gS[slot*64 + t], sS[t]); atomicAdd(&gQ[slot*64 + t], sQ[t]); }
}

// ---------- finalize BN stats (sum 32 copies) ----------
__global__ __launch_bounds__(128) void k_finalize(const float* __restrict__ S, const float* __restrict__ Q,
                                                  const float* __restrict__ g, const float* __restrict__ bb_,
                                                  float* __restrict__ A, float* __restrict__ Bt, int ch) {
  int t = threadIdx.x;
  if (t < ch) {
    float s = 0.f, qq = 0.f;
    for (int c = 0; c < 32; ++c) { s += S[c*ch + t]; qq += Q[c*ch + t]; }
    float mean = s * (1.0f / NPOSF);
    float var  = qq * (1.0f / NPOSF) - mean*mean;
    float rs   = 1.0f / sqrtf(var + BNEPS);
    float a    = g[t] * rs;
    A[t] = a; Bt[t] = bb_[t] - mean*a;
  }
}

// ---------- layer 1 ----------
__global__ __launch_bounds__(256) void k_layer1(
    const unsigned short* __restrict__ Y0, const float* __restrict__ A0, const float* __restrict__ B0,
    const float* __restrict__ Wt1, unsigned short* __restrict__ Y1,
    float* __restrict__ gS, float* __restrict__ gQ) {
  extern __shared__ float sm[];
  float* wsL = sm;            // 4096
  float* xs  = sm + 4096;     // 4096
  float* aL  = sm + 8192;     // 64
  float* bL  = aL + 64;       // 64
  float* sS  = bL + 64;       // 64
  float* sQ  = sS + 64;       // 64

  const int t = threadIdx.x;
  const int b = blockIdx.y, n0 = blockIdx.x * 4;
  for (int i = t; i < 1024; i += 256) ((float4*)wsL)[i] = ((const float4*)Wt1)[i];
  if (t < 64)  { aL[t] = A0[t]; bL[t] = B0[t]; }
  if (t < 128) { sS[t] = 0.f; }
  __syncthreads();

  const int w = t >> 6, lane = t & 63, kq = lane >> 2, cg = lane & 3;
  const int n = n0 + w;
  float* xw = xs + w*1024;
  const unsigned short* yrow = Y0 + (((size_t)(b*NN + n))*KK + kq)*64;
  #pragma unroll
  for (int it = 0; it < 4; ++it) {
    int c = it*16 + cg*4;
    ushort4 u = *(const ushort4*)(yrow + c);
    xw[(c + 0)*16 + kq] = fmaxf(bf2f(u.x)*aL[c + 0] + bL[c + 0], 0.f);
    xw[(c + 1)*16 + kq] = fmaxf(bf2f(u.y)*aL[c + 1] + bL[c + 1], 0.f);
    xw[(c + 2)*16 + kq] = fmaxf(bf2f(u.z)*aL[c + 2] + bL[c + 2], 0.f);
    xw[(c + 3)*16 + kq] = fmaxf(bf2f(u.w)*aL[c + 3] + bL[c + 3], 0.f);
  }
  __syncthreads();

  const int o4 = lane & 15, pg = lane >> 4;
  float4 a0 = {0,0,0,0}, a1 = {0,0,0,0}, a2 = {0,0,0,0}, a3 = {0,0,0,0};
  const float* wb = wsL + 4*o4;
  const float* xb = xw + 4*pg;
  #pragma unroll 4
  for (int c = 0; c < 64; ++c) {
    float4 w4 = *(const float4*)(wb + c*64);
    float4 xv = *(const float4*)(xb + c*16);
    FMA4(a0, w4, xv.x); FMA4(a1, w4, xv.y); FMA4(a2, w4, xv.z); FMA4(a3, w4, xv.w);
  }
  {
    size_t basep = ((size_t)(b*NN + n))*KK;
    store4bf(Y1 + (basep + pg*4 + 0)*64 + 4*o4, a0);
    store4bf(Y1 + (basep + pg*4 + 1)*64 + 4*o4, a1);
    store4bf(Y1 + (basep + pg*4 + 2)*64 + 4*o4, a2);
    store4bf(Y1 + (basep + pg*4 + 3)*64 + 4*o4, a3);
  }
  RED4(a0,a1,a2,a3, x, 4*o4 + 0)
  RED4(a0,a1,a2,a3, y, 4*o4 + 1)
  RED4(a0,a1,a2,a3, z, 4*o4 + 2)
  RED4(a0,a1,a2,a3, w, 4*o4 + 3)
  __syncthreads();
  const int slot = blockIdx.x & 31;
  if (t < 64) { atomicAdd(&gS[slot*64 + t], sS[t]); atomicAdd(&gQ[slot*64 + t], sQ[t]); }
}

// ---------- layer 2 stats ----------
__global__ __launch_bounds__(256) void k_l2stats(
    const unsigned short* __restrict__ Y1, const float* __restrict__ A1, const float* __restrict__ B1,
    const float* __restrict__ Wt2, float* __restrict__ gS, float* __restrict__ gQ) {
  extern __shared__ float sm[];
  float* wsL = sm;            // 8192
  float* xs  = sm + 8192;     // 4096
  float* aL  = sm + 12288;    // 64
  float* bL  = aL + 64;       // 64
  float* sS  = bL + 64;       // 128
  float* sQ  = sS + 128;      // 128

  const int t = threadIdx.x;
  const int b = blockIdx.y, n0 = blockIdx.x * 4;
  for (int i = t; i < 2048; i += 256) ((float4*)wsL)[i] = ((const float4*)Wt2)[i];
  if (t < 64) { aL[t] = A1[t]; bL[t] = B1[t]; }
  sS[t] = 0.f;
  __syncthreads();

  const int w = t >> 6, lane = t & 63, kq = lane >> 2, cg = lane & 3;
  const int n = n0 + w;
  float* xw = xs + w*1024;
  const unsigned short* yrow = Y1 + (((size_t)(b*NN + n))*KK + kq)*64;
  #pragma unroll
  for (int it = 0; it < 4; ++it) {
    int c = it*16 + cg*4;
    ushort4 u = *(const ushort4*)(yrow + c);
    xw[(c + 0)*16 + kq] = fmaxf(bf2f(u.x)*aL[c + 0] + bL[c + 0], 0.f);
    xw[(c + 1)*16 + kq] = fmaxf(bf2f(u.y)*aL[c + 1] + bL[c + 1], 0.f);
    xw[(c + 2)*16 + kq] = fmaxf(bf2f(u.z)*aL[c + 2] + bL[c + 2], 0.f);
    xw[(c + 3)*16 + kq] = fmaxf(bf2f(u.w)*aL[c + 3] + bL[c + 3], 0.f);
  }
  __syncthreads();

  const int o4 = lane & 15, pg = lane >> 4;
  float4 c00={0,0,0,0},c01={0,0,0,0},c02={0,0,0,0},c03={0,0,0,0};
  float4 c10={0,0,0,0},c11={0,0,0,0},c12={0,0,0,0},c13={0,0,0,0};
  const float* wbA = wsL + 4*o4;
  const float* wbB = wsL + 64 + 4*o4;
  const float* xb  = xw + 4*pg;
  #pragma unroll 4
  for (int c = 0; c < 64; ++c) {
    float4 xv = *(const float4*)(xb + c*16);
    float4 wA = *(const float4*)(wbA + c*128);
    float4 wB = *(const float4*)(wbB + c*128);
    FMA4(c00, wA, xv.x); FMA4(c01, wA, xv.y); FMA4(c02, wA, xv.z); FMA4(c03, wA, xv.w);
    FMA4(c10, wB, xv.x); FMA4(c11, wB, xv.y); FMA4(c12, wB, xv.z); FMA4(c13, wB, xv.w);
  }
  RED4(c00,c01,c02,c03, x, 4*o4 + 0)
  RED4(c00,c01,c02,c03, y, 4*o4 + 1)
  RED4(c00,c01,c02,c03, z, 4*o4 + 2)
  RED4(c00,c01,c02,c03, w, 4*o4 + 3)
  RED4(c10,c11,c12,c13, x, 64 + 4*o4 + 0)
  RED4(c10,c11,c12,c13, y, 64 + 4*o4 + 1)
  RED4(c10,c11,c12,c13, z, 64 + 4*o4 + 2)
  RED4(c10,c11,c12,c13, w, 64 + 4*o4 + 3)
  __syncthreads();
  const int slot = blockIdx.x & 31;
  if (t < 128) { atomicAdd(&gS[slot*128 + t], sS[t]); atomicAdd(&gQ[slot*128 + t], sQ[t]); }
}

#define MAXC(A0_,A1_,A2_,A3_, comp, chidx) { \
  int ch_ = (chidx); float al_ = aL2[ch_], be_ = bL2[ch_]; \
  float m_ = fmaxf(al_*A0_.comp + be_, 0.f); \
  m_ = fmaxf(m_, fmaxf(al_*A1_.comp + be_, 0.f)); \
  m_ = fmaxf(m_, fmaxf(al_*A2_.comp + be_, 0.f)); \
  m_ = fmaxf(m_, fmaxf(al_*A3_.comp + be_, 0.f)); \
  m_ = fmaxf(m_, __shfl_xor(m_, 16)); m_ = fmaxf(m_, __shfl_xor(m_, 32)); \
  if (pg == 0) oBuf[w*128 + ch_] = m_; \
}

__global__ __launch_bounds__(256) void k_l2final(
    const unsigned short* __restrict__ Y1, const float* __restrict__ A1, const float* __restrict__ B1,
    const float* __restrict__ Wt2, const float* __restrict__ A2, const float* __restrict__ B2,
    float* __restrict__ outF) {
  extern __shared__ float sm[];
  float* wsL  = sm;            // 8192
  float* xs   = sm + 8192;     // 4096
  float* aL   = sm + 12288;    // 64
  float* bL   = aL + 64;       // 64
  float* aL2  = bL + 64;       // 128
  float* bL2  = aL2 + 128;     // 128
  float* oBuf = bL2 + 128;     // 512

  const int t = threadIdx.x;
  const int b = blockIdx.y, n0 = blockIdx.x * 4;
  for (int i = t; i < 2048; i += 256) ((float4*)wsL)[i] = ((const float4*)Wt2)[i];
  if (t < 64)  { aL[t] = A1[t]; bL[t] = B1[t]; }
  if (t < 128) { aL2[t] = A2[t]; bL2[t] = B2[t]; }
  __syncthreads();

  const int w = t >> 6, lane = t & 63, kq = lane >> 2, cg = lane & 3;
  const int n = n0 + w;
  float* xw = xs + w*1024;
  const unsigned short* yrow = Y1 + (((size_t)(b*NN + n))*KK + kq)*64;
  #pragma unroll
  for (int it = 0; it < 4; ++it) {
    int c = it*16 + cg*4;
    ushort4 u = *(const ushort4*)(yrow + c);
    xw[(c + 0)*16 + kq] = fmaxf(bf2f(u.x)*aL[c + 0] + bL[c + 0], 0.f);
    xw[(c + 1)*16 + kq] = fmaxf(bf2f(u.y)*aL[c + 1] + bL[c + 1], 0.f);
    xw[(c + 2)*16 + kq] = fmaxf(bf2f(u.z)*aL[c + 2] + bL[c + 2], 0.f);
    xw[(c + 3)*16 + kq] = fmaxf(bf2f(u.w)*aL[c + 3] + bL[c + 3], 0.f);
  }
  __syncthreads();

  const int o4 = lane & 15, pg = lane >> 4;
  float4 c00={0,0,0,0},c01={0,0,0,0},c02={0,0,0,0},c03={0,0,0,0};
  float4 c10={0,0,0,0},c11={0,0,0,0},c12={0,0,0,0},c13={0,0,0,0};
  const float* wbA = wsL + 4*o4;
  const float* wbB = wsL + 64 + 4*o4;
  const float* xb  = xw + 4*pg;
  #pragma unroll 4
  for (int c = 0; c < 64; ++c) {
    float4 xv = *(const float4*)(xb + c*16);
    float4 wA = *(const float4*)(wbA + c*128);
    float4 wB = *(const float4*)(wbB + c*128);
    FMA4(c00, wA, xv.x); FMA4(c01, wA, xv.y); FMA4(c02, wA, xv.z); FMA4(c03, wA, xv.w);
    FMA4(c10, wB, xv.x); FMA4(c11, wB, xv.y); FMA4(c12, wB, xv.z); FMA4(c13, wB, xv.w);
  }
  MAXC(c00,c01,c02,c03, x, 4*o4 + 0)
  MAXC(c00,c01,c02,c03, y, 4*o4 + 1)
  MAXC(c00,c01,c02,c03, z, 4*o4 + 2)
  MAXC(c00,c01,c02,c03, w, 4*o4 + 3)
  MAXC(c10,c11,c12,c13, x, 64 + 4*o4 + 0)
  MAXC(c10,c11,c12,c13, y, 64 + 4*o4 + 1)
  MAXC(c10,c11,c12,c13, z, 64 + 4*o4 + 2)
  MAXC(c10,c11,c12,c13, w, 64 + 4*o4 + 3)
  __syncthreads();
  #pragma unroll
  for (int e = t; e < 512; e += 256) {
    int ch = e >> 2, nl = e & 3;
    outF[((size_t)b*H2 + ch)*NN + n0 + nl] = oBuf[nl*128 + ch];
  }
}

// ---------- launch ----------
extern "C" void kernel_launch(void* const* d_in, const int* in_sizes, int n_in,
                              void* d_out, int out_size, void* d_ws, size_t ws_size,
                              hipStream_t stream) {
  const float* pos1    = (const float*)d_in[0];
  const float* pos1_re = (const float*)d_in[1];
  const float* pos2    = (const float*)d_in[2];
  const float* f1      = (const float*)d_in[3];
  const float* f2      = (const float*)d_in[4];
  const float* W0 = (const float*)d_in[6];
  const float* g0 = (const float*)d_in[7];
  const float* b0 = (const float*)d_in[8];
  const float* W1 = (const float*)d_in[9];
  const float* g1 = (const float*)d_in[10];
  const float* b1 = (const float*)d_in[11];
  const float* W2 = (const float*)d_in[12];
  const float* g2 = (const float*)d_in[13];
  const float* b2 = (const float*)d_in[14];
  float* out = (float*)d_out;

  // workspace layout (bytes)
  char* ws = (char*)d_ws;
  float* stats = (float*)ws;                 // 16384 floats @0 (65536 B)
  float* S0 = stats;         float* Q0 = stats + 2048;
  float* S1 = stats + 4096;  float* Q1 = stats + 6144;
  float* S2 = stats + 8192;  float* Q2 = stats + 12288;
  float* prm = (float*)(ws + 65536);         // 512 floats
  float* A0 = prm;       float* B0a = prm + 64;
  float* A1 = prm + 128; float* B1a = prm + 192;
  float* A2 = prm + 256; float* B2a = prm + 384;
  float* Wt0 = (float*)(ws + 67584);         // 8384 f
  float* Wt1 = (float*)(ws + 101120);        // 4096 f
  float* Wt2 = (float*)(ws + 117504);        // 8192 f -> ends 150272
  unsigned short* idxb = (unsigned short*)(ws + 150528);   // 1,048,576 B
  float4* pos2t = (float4*)(ws + 1199104);   // 524,288 B
  float*  f2t   = (float*)(ws + 1723392);    // 8 MB
  float*  f1t   = (float*)(ws + 10112000);   // 8 MB
  unsigned short* Y0 = (unsigned short*)(ws + 18500608);   // 64 MB
  unsigned short* Y1 = (unsigned short*)(ws + 85609472);   // 64 MB -> ends 152,718,336
  if (ws_size < 152718336u) return;

  k_zero<<<dim3(64), 256, 0, stream>>>(stats);
  k_wt<<<dim3(81), 256, 0, stream>>>(W0, W1, W2, Wt0, Wt1, Wt2);
  hipMemcpyAsync(out, pos1, (size_t)BB*3*NN*sizeof(float), hipMemcpyDeviceToDevice, stream);

  k_pos2t<<<dim3(BB*NN/256), 256, 0, stream>>>(pos2, pos2t);
  k_transpose<<<dim3(NN/32, CC/32, BB), dim3(32, 8), 0, stream>>>(f2, f2t);
  k_transpose<<<dim3(NN/32, CC/32, BB), dim3(32, 8), 0, stream>>>(f1, f1t);
  k_knn<<<dim3(NN/128, BB), 128, 2048*sizeof(float4), stream>>>(pos1_re, pos2t, idxb);

  k_layer0<<<dim3(NN/2, BB), 128, 12736*4, stream>>>(idxb, pos2t, pos1, f2t, f1t, Wt0, Y0, S0, Q0);
  k_finalize<<<1, 128, 0, stream>>>(S0, Q0, g0, b0, A0, B0a, 64);

  k_layer1<<<dim3(NN/4, BB), 256, 8448*4, stream>>>(Y0, A0, B0a, Wt1, Y1, S1, Q1);
  k_finalize<<<1, 128, 0, stream>>>(S1, Q1, g1, b1, A1, B1a, 64);

  k_l2stats<<<dim3(NN/4, BB), 256, 12672*4, stream>>>(Y1, A1, B1a, Wt2, S2, Q2);
  k_finalize<<<1, 128, 0, stream>>>(S2, Q2, g2, b2, A2, B2a, 128);

  k_l2final<<<dim3(NN/4, BB), 256, 13184*4, stream>>>(Y1, A1, B1a, Wt2, A2, B2a, out + (size_t)BB*3*NN);
}